// Round 1
// baseline (2100.285 us; speedup 1.0000x reference)
//
#include <hip/hip_runtime.h>
#include <hip/hip_bf16.h>

#define EPS 1e-6f

// ---------------------------------------------------------------------------
// Kernel 1: proj[m][n] = sum_k x[m][k] * W[n][k]   (A * B^T, both K-major)
//   M = T*B = 32768, N = 256, K = 1024, fp32 (no fp32 MFMA on CDNA4 -> VALU)
//   64x64x64 tiles, 256 threads, 4x4 micro-tile per thread.
// ---------------------------------------------------------------------------
constexpr int BM = 64, BN = 64, BK = 64;

__global__ __launch_bounds__(256) void proj_gemm(
    const float* __restrict__ A,   // [M][K]  (x)
    const float* __restrict__ Bw,  // [N][K]  (W_kvqm)
    float* __restrict__ C,         // [M][N]  (proj)
    int M, int N, int K) {
  // k-major LDS tiles so the inner loop reads contiguous float4 per thread.
  __shared__ float As[BK][BM + 4];
  __shared__ float Bs[BK][BN + 4];

  const int tid = threadIdx.x;
  const int m0 = blockIdx.x * BM;
  const int n0 = blockIdx.y * BN;
  const int tr = tid & 15;   // 0..15 -> rows  tr*4 .. tr*4+3
  const int tc = tid >> 4;   // 0..15 -> cols  tc*4 .. tc*4+3

  float acc[4][4] = {};

  for (int k0 = 0; k0 < K; k0 += BK) {
#pragma unroll
    for (int rep = 0; rep < 4; ++rep) {
      int idx = rep * 256 + tid;
      int r  = idx >> 4;        // 0..63 (tile row)
      int c4 = idx & 15;        // 0..15 (float4 index along k)
      float4 va = *(const float4*)&A[(size_t)(m0 + r) * K + k0 + c4 * 4];
      As[c4 * 4 + 0][r] = va.x;
      As[c4 * 4 + 1][r] = va.y;
      As[c4 * 4 + 2][r] = va.z;
      As[c4 * 4 + 3][r] = va.w;
      float4 vb = *(const float4*)&Bw[(size_t)(n0 + r) * K + k0 + c4 * 4];
      Bs[c4 * 4 + 0][r] = vb.x;
      Bs[c4 * 4 + 1][r] = vb.y;
      Bs[c4 * 4 + 2][r] = vb.z;
      Bs[c4 * 4 + 3][r] = vb.w;
    }
    __syncthreads();

#pragma unroll 8
    for (int k = 0; k < BK; ++k) {
      float4 a = *(const float4*)&As[k][tr * 4];
      float4 b = *(const float4*)&Bs[k][tc * 4];
      float av[4] = {a.x, a.y, a.z, a.w};
      float bv[4] = {b.x, b.y, b.z, b.w};
#pragma unroll
      for (int i = 0; i < 4; ++i)
#pragma unroll
        for (int j = 0; j < 4; ++j)
          acc[i][j] = fmaf(av[i], bv[j], acc[i][j]);
    }
    __syncthreads();
  }

#pragma unroll
  for (int i = 0; i < 4; ++i) {
    float4 o = make_float4(acc[i][0], acc[i][1], acc[i][2], acc[i][3]);
    *(float4*)&C[(size_t)(m0 + tr * 4 + i) * N + n0 + tc * 4] = o;
  }
}

// ---------------------------------------------------------------------------
// Kernel 2: the sequential scan. One wave per (batch b, row i); lane j holds
// S[b,i,j] and G[b,i,j] in registers across all T steps.
// ---------------------------------------------------------------------------
__device__ __forceinline__ float wave_sum(float v) {
#pragma unroll
  for (int m = 32; m > 0; m >>= 1) v += __shfl_xor(v, m, 64);
  return v;
}

__device__ __forceinline__ float sigmoidf(float x) {
  return __builtin_amdgcn_rcpf(1.0f + __expf(-x));
}

__global__ __launch_bounds__(256) void e81_scan(
    const float* __restrict__ proj,  // [T*16][256] : k|v|q|m each 64
    const float* __restrict__ S0,    // [16][64][64]
    const float* __restrict__ G0,
    const float* __restrict__ bsg,   // [64]
    const float* __restrict__ bgg,   // [64]
    float* __restrict__ dout,        // out[T*16*64] ++ S[16*64*64] ++ G[...]
    int T) {
  const int lane = threadIdx.x & 63;
  const int wave = threadIdx.x >> 6;           // 0..3
  const int b    = blockIdx.x >> 4;            // 0..15
  const int row  = ((blockIdx.x & 15) << 2) + wave;  // 0..63

  const int sg_idx = (((b << 6) + row) << 6) + lane;  // [b][row][lane]
  float S = S0[sg_idx];
  float G = G0[sg_idx];
  const float bsi = bsg[row];
  const float bgi = bgg[row];

  float* outp = dout;
  float* Sout = dout + (size_t)T * 16 * 64;
  float* Gout = Sout + 16 * 64 * 64;

  const float* p = proj + b * 256;
  float kj = p[lane];
  float vi = p[64 + row];
  float qj = p[128 + lane];
  float mj = p[192 + lane];

  for (int t = 0; t < T; ++t) {
    // software prefetch of next step's k/v/q/m (state-independent loads;
    // they issue before the reduce chain and retire under it)
    const float* pn = (t + 1 < T) ? (p + 16 * 256) : p;
    float kjn = pn[lane];
    float vin = pn[64 + row];
    float qjn = pn[128 + lane];
    float mjn = pn[192 + lane];

    float invk = __builtin_amdgcn_rcpf(sqrtf(wave_sum(kj * kj)) + EPS);
    float invm = __builtin_amdgcn_rcpf(sqrtf(wave_sum(mj * mj)) + EPS);
    float khat = kj * invk;
    float mhat = mj * invm;

    float sr = wave_sum(S * khat);          // S_old . k_hat
    float gr = wave_sum(G * mhat);          // G_old . m_hat (old G!)
    float sdelta = vi - sr;
    float gateS = sigmoidf(G + bsi);
    S = fmaf(gateS, S, sdelta * khat);      // S_new
    float gateG = sigmoidf(S + bgi);        // uses S_new
    float gdelta = sdelta - gr;
    G = fmaf(gateG, G, gdelta * mhat);      // G_new

    float sq = wave_sum(S * qj);            // S_new . q
    if (lane == 0)
      outp[(((size_t)t << 4) + b) * 64 + row] = sq * sq * sigmoidf(sq);

    kj = kjn; vi = vin; qj = qjn; mj = mjn;
    p = pn;
  }

  Sout[sg_idx] = S;
  Gout[sg_idx] = G;
}

// ---------------------------------------------------------------------------
extern "C" void kernel_launch(void* const* d_in, const int* in_sizes, int n_in,
                              void* d_out, int out_size, void* d_ws, size_t ws_size,
                              hipStream_t stream) {
  const float* x  = (const float*)d_in[0];  // (T,16,1024)
  const float* S0 = (const float*)d_in[1];  // (16,64,64)
  const float* G0 = (const float*)d_in[2];
  const float* W  = (const float*)d_in[3];  // (256,1024)
  const float* bs = (const float*)d_in[4];  // (64)
  const float* bg = (const float*)d_in[5];  // (64)
  float* out = (float*)d_out;
  float* proj = (float*)d_ws;               // [T*16][256] = 32 MB

  const int B = 16, D = 1024, N4 = 256;
  const int T = in_sizes[0] / (B * D);      // 2048
  const int M = T * B;                      // 32768

  dim3 g1(M / BM, N4 / BN);                 // (512, 4)
  proj_gemm<<<g1, 256, 0, stream>>>(x, W, proj, M, N4, D);

  e81_scan<<<dim3(256), 256, 0, stream>>>(proj, S0, G0, bs, bg, out, T);
}

// Round 5
// 934.416 us; speedup vs baseline: 2.2477x; 2.2477x over previous
//
#include <hip/hip_runtime.h>
#include <hip/hip_bf16.h>

#define EPS 1e-6f

typedef float f32x4 __attribute__((ext_vector_type(4)));
typedef short bf16x8 __attribute__((ext_vector_type(8)));

// ---------------------------------------------------------------------------
// bf16 hi/lo split helpers. u32 element = (lo16 << 16) | hi16.
// x = hi + lo exactly to ~2^-16 relative (x - float(hi) is exact).
// ---------------------------------------------------------------------------
__device__ __forceinline__ unsigned f2bf(float x) {
  __hip_bfloat16 h = __float2bfloat16(x);
  return *reinterpret_cast<unsigned short*>(&h);
}
__device__ __forceinline__ unsigned split_pack(float x) {
  unsigned hi = f2bf(x);
  unsigned short hs = (unsigned short)hi;
  float hif = __bfloat162float(*reinterpret_cast<__hip_bfloat16*>(&hs));
  unsigned lo = f2bf(x - hif);
  return (lo << 16) | hi;
}

union FragCast { unsigned u[4]; bf16x8 v; };

// ---------------------------------------------------------------------------
// Kernel 1: proj = x @ W^T via bf16-split MFMA.
//   M=32768, N=256 (full width per block), K=1024.
//   Block: 512 thr = 8 waves (2x4), tile 128x256, per-wave 64x64.
//   LDS u32 tiles hold (lo,hi) bf16 pairs; rows XOR-swizzled (G4 b128 fix).
//   3 MFMA terms: ah*bh + ah*bl + al*bh  (al*bl dropped, ~2^-16 rel).
// ---------------------------------------------------------------------------
constexpr int GBM = 128, GBK = 32;

__global__ __launch_bounds__(512) void proj_gemm_mfma(
    const float* __restrict__ A,   // [M][1024]  x
    const float* __restrict__ Bw,  // [256][1024] W_kvqm
    float* __restrict__ C,         // [M][256]   proj
    int M, int K) {
  __shared__ unsigned As[GBM * GBK];   // 16 KB, row stride 32 u32 = 128 B
  __shared__ unsigned Bs[256 * GBK];   // 32 KB

  const int tid  = threadIdx.x;
  const int lane = tid & 63;
  const int wid  = tid >> 6;
  const int m0   = blockIdx.x * GBM;
  const int wm   = (wid >> 2) * 64;    // wave m-offset within tile
  const int wn   = (wid & 3) * 64;     // wave n-offset

  // staging assignment: A: thread -> (row=t>>2, k=(t&3)*8 .. +7)
  //                     B: thread -> (row=t>>1, k=(t&1)*16 .. +15)
  const int ar = tid >> 2, ak = (tid & 3) * 8;
  const int br = tid >> 1, bk = (tid & 1) * 16;

  f32x4 acc[4][4] = {};

  for (int k0 = 0; k0 < K; k0 += GBK) {
    // ---- stage A (128x32 fp32 -> split u32, swizzled ds_write_b128) ----
    {
      const float* src = &A[(size_t)(m0 + ar) * K + k0 + ak];
      float4 v0 = *(const float4*)(src);
      float4 v1 = *(const float4*)(src + 4);
      unsigned p0[4] = {split_pack(v0.x), split_pack(v0.y),
                        split_pack(v0.z), split_pack(v0.w)};
      unsigned p1[4] = {split_pack(v1.x), split_pack(v1.y),
                        split_pack(v1.z), split_pack(v1.w)};
      unsigned swz  = (unsigned)(ar & 7) << 4;
      char* base = (char*)As + ar * 128;
      *(uint4*)(base + (((unsigned)ak * 4) ^ swz))       = *(uint4*)p0;
      *(uint4*)(base + (((unsigned)(ak + 4) * 4) ^ swz)) = *(uint4*)p1;
    }
    // ---- stage B (256x32) ----
    {
      const float* src = &Bw[(size_t)br * K + k0 + bk];
      unsigned swz = (unsigned)(br & 7) << 4;
      char* base = (char*)Bs + br * 128;
#pragma unroll
      for (int q = 0; q < 4; ++q) {
        float4 v = *(const float4*)(src + q * 4);
        unsigned p[4] = {split_pack(v.x), split_pack(v.y),
                         split_pack(v.z), split_pack(v.w)};
        *(uint4*)(base + (((unsigned)(bk + q * 4) * 4) ^ swz)) = *(uint4*)p;
      }
    }
    __syncthreads();

    // ---- A fragments: 4 m-frags, each 2x b128 (k-halves 0-15,16-31) ----
    // frag elem j <-> k = 4*(lane>>4) + (j&3) + 16*(j>>2)
    unsigned ah[4][4], al[4][4];
    const unsigned ko = ((unsigned)(lane >> 4)) * 16;  // byte offs of k-quad
#pragma unroll
    for (int mf = 0; mf < 4; ++mf) {
      int r = wm + mf * 16 + (lane & 15);
      unsigned swz = (unsigned)(r & 7) << 4;
      char* base = (char*)As + r * 128;
      uint4 w0 = *(uint4*)(base + (ko ^ swz));
      uint4 w1 = *(uint4*)(base + ((64 + ko) ^ swz));
      ah[mf][0] = __builtin_amdgcn_perm(w0.y, w0.x, 0x05040100);
      al[mf][0] = __builtin_amdgcn_perm(w0.y, w0.x, 0x07060302);
      ah[mf][1] = __builtin_amdgcn_perm(w0.w, w0.z, 0x05040100);
      al[mf][1] = __builtin_amdgcn_perm(w0.w, w0.z, 0x07060302);
      ah[mf][2] = __builtin_amdgcn_perm(w1.y, w1.x, 0x05040100);
      al[mf][2] = __builtin_amdgcn_perm(w1.y, w1.x, 0x07060302);
      ah[mf][3] = __builtin_amdgcn_perm(w1.w, w1.z, 0x05040100);
      al[mf][3] = __builtin_amdgcn_perm(w1.w, w1.z, 0x07060302);
    }

#pragma unroll
    for (int nf = 0; nf < 4; ++nf) {
      int r = wn + nf * 16 + (lane & 15);
      unsigned swz = (unsigned)(r & 7) << 4;
      char* base = (char*)Bs + r * 128;
      uint4 w0 = *(uint4*)(base + (ko ^ swz));
      uint4 w1 = *(uint4*)(base + ((64 + ko) ^ swz));
      FragCast bh, bl;
      bh.u[0] = __builtin_amdgcn_perm(w0.y, w0.x, 0x05040100);
      bl.u[0] = __builtin_amdgcn_perm(w0.y, w0.x, 0x07060302);
      bh.u[1] = __builtin_amdgcn_perm(w0.w, w0.z, 0x05040100);
      bl.u[1] = __builtin_amdgcn_perm(w0.w, w0.z, 0x07060302);
      bh.u[2] = __builtin_amdgcn_perm(w1.y, w1.x, 0x05040100);
      bl.u[2] = __builtin_amdgcn_perm(w1.y, w1.x, 0x07060302);
      bh.u[3] = __builtin_amdgcn_perm(w1.w, w1.z, 0x05040100);
      bl.u[3] = __builtin_amdgcn_perm(w1.w, w1.z, 0x07060302);
#pragma unroll
      for (int mf = 0; mf < 4; ++mf) {
        FragCast fah, fal;
        fah.u[0] = ah[mf][0]; fah.u[1] = ah[mf][1];
        fah.u[2] = ah[mf][2]; fah.u[3] = ah[mf][3];
        fal.u[0] = al[mf][0]; fal.u[1] = al[mf][1];
        fal.u[2] = al[mf][2]; fal.u[3] = al[mf][3];
        acc[mf][nf] = __builtin_amdgcn_mfma_f32_16x16x32_bf16(
            fah.v, bh.v, acc[mf][nf], 0, 0, 0);
        acc[mf][nf] = __builtin_amdgcn_mfma_f32_16x16x32_bf16(
            fah.v, bl.v, acc[mf][nf], 0, 0, 0);
        acc[mf][nf] = __builtin_amdgcn_mfma_f32_16x16x32_bf16(
            fal.v, bh.v, acc[mf][nf], 0, 0, 0);
      }
    }
    __syncthreads();
  }

  // epilogue: C/D map (m89-verified): col=lane&15, row=(lane>>4)*4+reg
#pragma unroll
  for (int mf = 0; mf < 4; ++mf) {
    int row = m0 + wm + mf * 16 + (lane >> 4) * 4;
#pragma unroll
    for (int nf = 0; nf < 4; ++nf) {
      int col = wn + nf * 16 + (lane & 15);
#pragma unroll
      for (int r = 0; r < 4; ++r)
        C[(size_t)(row + r) * 256 + col] = acc[mf][nf][r];
    }
  }
}

// ---------------------------------------------------------------------------
// DPP sum-to-all-lanes (VALU-only, ~60-80 cy vs ~720 for ds-pipe shuffles)
// ---------------------------------------------------------------------------
template <int CTRL>
__device__ __forceinline__ float dpp_mov(float v) {
  return __int_as_float(
      __builtin_amdgcn_update_dpp(0, __float_as_int(v), CTRL, 0xF, 0xF, true));
}

__device__ __forceinline__ float wave_sum_all(float v) {
  v += dpp_mov<0x121>(v);  // row_ror:1
  v += dpp_mov<0x122>(v);  // row_ror:2
  v += dpp_mov<0x124>(v);  // row_ror:4
  v += dpp_mov<0x128>(v);  // row_ror:8   -> 16-lane row totals everywhere
  v += dpp_mov<0x142>(v);  // row_bcast15 -> lanes48-63 hold rows2+3 partials
  v += dpp_mov<0x143>(v);  // row_bcast31 -> lanes48-63 hold full total
  return __int_as_float(__builtin_amdgcn_readlane(__float_as_int(v), 63));
}

__device__ __forceinline__ float sigmoidf(float x) {
  return __builtin_amdgcn_rcpf(1.0f + __expf(-x));
}

// ---------------------------------------------------------------------------
// Kernel 2: normalize k and m in-place in proj (hoisted out of the scan).
// ---------------------------------------------------------------------------
__global__ __launch_bounds__(256) void normalize_km(float* __restrict__ proj,
                                                    int rows) {
  const int w = blockIdx.x * 4 + (threadIdx.x >> 6);
  const int lane = threadIdx.x & 63;
  if (w >= rows) return;
  float* p = proj + (size_t)w * 256;
  float k = p[lane];
  float m = p[192 + lane];
  float nk = sqrtf(wave_sum_all(k * k)) + EPS;
  float nm = sqrtf(wave_sum_all(m * m)) + EPS;
  p[lane]       = k * __builtin_amdgcn_rcpf(nk);
  p[192 + lane] = m * __builtin_amdgcn_rcpf(nm);
}

// ---------------------------------------------------------------------------
// Kernel 3: sequential scan. One wave per (batch b, row i); lane j holds
// S[b,i,j], G[b,i,j] in registers. k/m pre-normalized.
// ---------------------------------------------------------------------------
__global__ __launch_bounds__(256) void e81_scan(
    const float* __restrict__ proj,  // [T*16][256] : khat|v|q|mhat
    const float* __restrict__ S0,
    const float* __restrict__ G0,
    const float* __restrict__ bsg,
    const float* __restrict__ bgg,
    float* __restrict__ dout,
    int T) {
  const int lane = threadIdx.x & 63;
  const int wave = threadIdx.x >> 6;
  const int b    = blockIdx.x >> 4;
  const int row  = ((blockIdx.x & 15) << 2) + wave;

  const int sg_idx = (((b << 6) + row) << 6) + lane;
  float S = S0[sg_idx];
  float G = G0[sg_idx];
  const float bsi = bsg[row];
  const float bgi = bgg[row];

  float* outp = dout;
  float* Sout = dout + (size_t)T * 16 * 64;
  float* Gout = Sout + 16 * 64 * 64;

  const float* p = proj + b * 256;
  float kj = p[lane];
  float vi = p[64 + row];
  float qj = p[128 + lane];
  float mj = p[192 + lane];

  for (int t = 0; t < T; ++t) {
    const float* pn = (t + 1 < T) ? (p + 16 * 256) : p;
    float kjn = pn[lane];
    float vin = pn[64 + row];
    float qjn = pn[128 + lane];
    float mjn = pn[192 + lane];

    float sr = wave_sum_all(S * kj);   // S_old . k_hat
    float gr = wave_sum_all(G * mj);   // G_old . m_hat
    float gateS = sigmoidf(G + bsi);
    float sdelta = vi - sr;
    S = fmaf(gateS, S, sdelta * kj);
    float gateG = sigmoidf(S + bgi);
    G = fmaf(gateG, G, (sdelta - gr) * mj);

    float sq = wave_sum_all(S * qj);
    if (lane == 0)
      outp[(((size_t)t << 4) + b) * 64 + row] = sq * sq * sigmoidf(sq);

    kj = kjn; vi = vin; qj = qjn; mj = mjn;
    p = pn;
  }

  Sout[sg_idx] = S;
  Gout[sg_idx] = G;
}

// ---------------------------------------------------------------------------
extern "C" void kernel_launch(void* const* d_in, const int* in_sizes, int n_in,
                              void* d_out, int out_size, void* d_ws, size_t ws_size,
                              hipStream_t stream) {
  const float* x  = (const float*)d_in[0];
  const float* S0 = (const float*)d_in[1];
  const float* G0 = (const float*)d_in[2];
  const float* W  = (const float*)d_in[3];
  const float* bs = (const float*)d_in[4];
  const float* bg = (const float*)d_in[5];
  float* out = (float*)d_out;
  float* proj = (float*)d_ws;               // [M][256] = 32 MB

  const int B = 16, D = 1024;
  const int T = in_sizes[0] / (B * D);      // 2048
  const int M = T * B;                      // 32768

  proj_gemm_mfma<<<dim3(M / GBM), 512, 0, stream>>>(x, W, proj, M, D);

  normalize_km<<<dim3(M / 4), 256, 0, stream>>>(proj, M);

  e81_scan<<<dim3(256), 256, 0, stream>>>(proj, S0, G0, bs, bg, out, T);
}

// Round 6
// 885.513 us; speedup vs baseline: 2.3718x; 1.0552x over previous
//
#include <hip/hip_runtime.h>
#include <hip/hip_bf16.h>

#define EPS 1e-6f

typedef float f32x4 __attribute__((ext_vector_type(4)));
typedef short bf16x8 __attribute__((ext_vector_type(8)));

// ---------------------------------------------------------------------------
// bf16 hi/lo split helpers. u32 element = (lo16 << 16) | hi16.
// ---------------------------------------------------------------------------
__device__ __forceinline__ unsigned f2bf(float x) {
  __hip_bfloat16 h = __float2bfloat16(x);
  return *reinterpret_cast<unsigned short*>(&h);
}
__device__ __forceinline__ unsigned split_pack(float x) {
  unsigned hi = f2bf(x);
  unsigned short hs = (unsigned short)hi;
  float hif = __bfloat162float(*reinterpret_cast<__hip_bfloat16*>(&hs));
  unsigned lo = f2bf(x - hif);
  return (lo << 16) | hi;
}

union FragCast { unsigned u[4]; bf16x8 v; };

// ---------------------------------------------------------------------------
// Kernel 1: proj = x @ W^T via bf16-split MFMA. (unchanged from round 5,
// measured-good; ~meas pending split vs normalize)
// ---------------------------------------------------------------------------
constexpr int GBM = 128, GBK = 32;

__global__ __launch_bounds__(512) void proj_gemm_mfma(
    const float* __restrict__ A,   // [M][1024]  x
    const float* __restrict__ Bw,  // [256][1024] W_kvqm
    float* __restrict__ C,         // [M][256]   proj
    int M, int K) {
  __shared__ unsigned As[GBM * GBK];
  __shared__ unsigned Bs[256 * GBK];

  const int tid  = threadIdx.x;
  const int lane = tid & 63;
  const int wid  = tid >> 6;
  const int m0   = blockIdx.x * GBM;
  const int wm   = (wid >> 2) * 64;
  const int wn   = (wid & 3) * 64;

  const int ar = tid >> 2, ak = (tid & 3) * 8;
  const int br = tid >> 1, bk = (tid & 1) * 16;

  f32x4 acc[4][4] = {};

  for (int k0 = 0; k0 < K; k0 += GBK) {
    {
      const float* src = &A[(size_t)(m0 + ar) * K + k0 + ak];
      float4 v0 = *(const float4*)(src);
      float4 v1 = *(const float4*)(src + 4);
      unsigned p0[4] = {split_pack(v0.x), split_pack(v0.y),
                        split_pack(v0.z), split_pack(v0.w)};
      unsigned p1[4] = {split_pack(v1.x), split_pack(v1.y),
                        split_pack(v1.z), split_pack(v1.w)};
      unsigned swz  = (unsigned)(ar & 7) << 4;
      char* base = (char*)As + ar * 128;
      *(uint4*)(base + (((unsigned)ak * 4) ^ swz))       = *(uint4*)p0;
      *(uint4*)(base + (((unsigned)(ak + 4) * 4) ^ swz)) = *(uint4*)p1;
    }
    {
      const float* src = &Bw[(size_t)br * K + k0 + bk];
      unsigned swz = (unsigned)(br & 7) << 4;
      char* base = (char*)Bs + br * 128;
#pragma unroll
      for (int q = 0; q < 4; ++q) {
        float4 v = *(const float4*)(src + q * 4);
        unsigned p[4] = {split_pack(v.x), split_pack(v.y),
                         split_pack(v.z), split_pack(v.w)};
        *(uint4*)(base + (((unsigned)(bk + q * 4) * 4) ^ swz)) = *(uint4*)p;
      }
    }
    __syncthreads();

    unsigned ah[4][4], al[4][4];
    const unsigned ko = ((unsigned)(lane >> 4)) * 16;
#pragma unroll
    for (int mf = 0; mf < 4; ++mf) {
      int r = wm + mf * 16 + (lane & 15);
      unsigned swz = (unsigned)(r & 7) << 4;
      char* base = (char*)As + r * 128;
      uint4 w0 = *(uint4*)(base + (ko ^ swz));
      uint4 w1 = *(uint4*)(base + ((64 + ko) ^ swz));
      ah[mf][0] = __builtin_amdgcn_perm(w0.y, w0.x, 0x05040100);
      al[mf][0] = __builtin_amdgcn_perm(w0.y, w0.x, 0x07060302);
      ah[mf][1] = __builtin_amdgcn_perm(w0.w, w0.z, 0x05040100);
      al[mf][1] = __builtin_amdgcn_perm(w0.w, w0.z, 0x07060302);
      ah[mf][2] = __builtin_amdgcn_perm(w1.y, w1.x, 0x05040100);
      al[mf][2] = __builtin_amdgcn_perm(w1.y, w1.x, 0x07060302);
      ah[mf][3] = __builtin_amdgcn_perm(w1.w, w1.z, 0x05040100);
      al[mf][3] = __builtin_amdgcn_perm(w1.w, w1.z, 0x07060302);
    }

#pragma unroll
    for (int nf = 0; nf < 4; ++nf) {
      int r = wn + nf * 16 + (lane & 15);
      unsigned swz = (unsigned)(r & 7) << 4;
      char* base = (char*)Bs + r * 128;
      uint4 w0 = *(uint4*)(base + (ko ^ swz));
      uint4 w1 = *(uint4*)(base + ((64 + ko) ^ swz));
      FragCast bh, bl;
      bh.u[0] = __builtin_amdgcn_perm(w0.y, w0.x, 0x05040100);
      bl.u[0] = __builtin_amdgcn_perm(w0.y, w0.x, 0x07060302);
      bh.u[1] = __builtin_amdgcn_perm(w0.w, w0.z, 0x05040100);
      bl.u[1] = __builtin_amdgcn_perm(w0.w, w0.z, 0x07060302);
      bh.u[2] = __builtin_amdgcn_perm(w1.y, w1.x, 0x05040100);
      bl.u[2] = __builtin_amdgcn_perm(w1.y, w1.x, 0x07060302);
      bh.u[3] = __builtin_amdgcn_perm(w1.w, w1.z, 0x05040100);
      bl.u[3] = __builtin_amdgcn_perm(w1.w, w1.z, 0x07060302);
#pragma unroll
      for (int mf = 0; mf < 4; ++mf) {
        FragCast fah, fal;
        fah.u[0] = ah[mf][0]; fah.u[1] = ah[mf][1];
        fah.u[2] = ah[mf][2]; fah.u[3] = ah[mf][3];
        fal.u[0] = al[mf][0]; fal.u[1] = al[mf][1];
        fal.u[2] = al[mf][2]; fal.u[3] = al[mf][3];
        acc[mf][nf] = __builtin_amdgcn_mfma_f32_16x16x32_bf16(
            fah.v, bh.v, acc[mf][nf], 0, 0, 0);
        acc[mf][nf] = __builtin_amdgcn_mfma_f32_16x16x32_bf16(
            fah.v, bl.v, acc[mf][nf], 0, 0, 0);
        acc[mf][nf] = __builtin_amdgcn_mfma_f32_16x16x32_bf16(
            fal.v, bh.v, acc[mf][nf], 0, 0, 0);
      }
    }
    __syncthreads();
  }

#pragma unroll
  for (int mf = 0; mf < 4; ++mf) {
    int row = m0 + wm + mf * 16 + (lane >> 4) * 4;
#pragma unroll
    for (int nf = 0; nf < 4; ++nf) {
      int col = wn + nf * 16 + (lane & 15);
#pragma unroll
      for (int r = 0; r < 4; ++r)
        C[(size_t)(row + r) * 256 + col] = acc[mf][nf][r];
    }
  }
}

// ---------------------------------------------------------------------------
// DPP helpers
// ---------------------------------------------------------------------------
template <int CTRL>
__device__ __forceinline__ float dpp_mov(float v) {
  return __int_as_float(
      __builtin_amdgcn_update_dpp(0, __float_as_int(v), CTRL, 0xF, 0xF, true));
}

// full 64-lane sum (6 hops + readlane) — used only in normalize_km
__device__ __forceinline__ float wave_sum_all(float v) {
  v += dpp_mov<0x121>(v);
  v += dpp_mov<0x122>(v);
  v += dpp_mov<0x124>(v);
  v += dpp_mov<0x128>(v);
  v += dpp_mov<0x142>(v);
  v += dpp_mov<0x143>(v);
  return __int_as_float(__builtin_amdgcn_readlane(__float_as_int(v), 63));
}

// 16-lane-row sum: after 4 row_ror hops every lane of each 16-row holds
// that row's total. No readlane, no SGPR round-trip. ~35 cy dependent.
__device__ __forceinline__ float reduce16(float v) {
  v += dpp_mov<0x121>(v);  // row_ror:1
  v += dpp_mov<0x122>(v);  // row_ror:2
  v += dpp_mov<0x124>(v);  // row_ror:4
  v += dpp_mov<0x128>(v);  // row_ror:8
  return v;
}

#define L2E 1.4426950408889634f
// sigmoid(x + b) with pre-scaled bias nb = -b*L2E:  rcp(1 + 2^(-x*L2E + nb))
__device__ __forceinline__ float sigm_b(float x, float nb) {
  float t = __builtin_amdgcn_exp2f(fmaf(x, -L2E, nb));
  return __builtin_amdgcn_rcpf(1.0f + t);
}
__device__ __forceinline__ float sigm(float x) {
  float t = __builtin_amdgcn_exp2f(x * -L2E);
  return __builtin_amdgcn_rcpf(1.0f + t);
}

// ---------------------------------------------------------------------------
// Kernel 2: normalize k,m AND permute k,q,m in-place to e-major order:
//   new[w] = old[16*(w&3) + (w>>2)]   (so scan lane l reads dwordx4 at 4l:
//   elements j = l, 16+l, 32+l, 48+l). Bijective -> norm reduce unaffected.
//   In-wave read-then-write is safe: stores' data depend on all prior loads
//   (vmcnt is in-order), and k/q/m regions are mutually disjoint.
// ---------------------------------------------------------------------------
__global__ __launch_bounds__(256) void normalize_km(float* __restrict__ proj,
                                                    int rows) {
  const int w = blockIdx.x * 4 + (threadIdx.x >> 6);
  const int lane = threadIdx.x & 63;
  if (w >= rows) return;
  float* p = proj + (size_t)w * 256;
  const int src = 16 * (lane & 3) + (lane >> 2);  // perm source index
  float k = p[src];
  float q = p[128 + src];
  float m = p[192 + src];
  float nk = sqrtf(wave_sum_all(k * k)) + EPS;
  float nm = sqrtf(wave_sum_all(m * m)) + EPS;
  p[lane]       = k * __builtin_amdgcn_rcpf(nk);
  p[128 + lane] = q;
  p[192 + lane] = m * __builtin_amdgcn_rcpf(nm);
}

// ---------------------------------------------------------------------------
// Kernel 3: scan, 4 rows per wave. lane = 16*g + l; g = row-group (0..3),
// l = 0..15. State S[e],G[e] hold element j = 16e+l of row (base+g).
// Reduce over j = in-lane e-sum (3 fma) + reduce16. 256 waves, 1/SIMD.
// ---------------------------------------------------------------------------
__global__ __launch_bounds__(64) void e81_scan(
    const float* __restrict__ proj,  // [T*16][256] : kT|v|qT|mT
    const float* __restrict__ S0,
    const float* __restrict__ G0,
    const float* __restrict__ bsg,
    const float* __restrict__ bgg,
    float* __restrict__ dout,
    int T) {
  const int lane = threadIdx.x;     // 0..63
  const int l = lane & 15;
  const int g = lane >> 4;
  const int b  = blockIdx.x >> 4;   // 0..15
  const int wb = blockIdx.x & 15;   // 0..15
  const int row = wb * 4 + g;

  const size_t sgbase = ((size_t)(b * 64 + row)) * 64 + l;  // j = 16e+l
  float S[4], G[4];
#pragma unroll
  for (int e = 0; e < 4; ++e) {
    S[e] = S0[sgbase + 16 * e];
    G[e] = G0[sgbase + 16 * e];
  }
  const float nbs = -bsg[row] * L2E;  // pre-scaled gate biases
  const float nbg = -bgg[row] * L2E;

  float* outp = dout;
  float* Sout = dout + (size_t)T * 16 * 64;
  float* Gout = Sout + 16 * 64 * 64;

  const float* p = proj + b * 256;
  float4 k = *(const float4*)(p + 4 * l);
  float4 q = *(const float4*)(p + 128 + 4 * l);
  float4 m = *(const float4*)(p + 192 + 4 * l);
  float  v = p[64 + row];

  for (int t = 0; t < T; ++t) {
    const float* pn = (t + 1 < T) ? (p + 16 * 256) : p;
    float4 kn = *(const float4*)(pn + 4 * l);
    float4 qn = *(const float4*)(pn + 128 + 4 * l);
    float4 mn = *(const float4*)(pn + 192 + 4 * l);
    float  vn = pn[64 + row];

    // sr = S_old . k_hat ; gr = G_old . m_hat  (per row-group)
    float sr = S[0] * k.x;
    sr = fmaf(S[1], k.y, sr);
    sr = fmaf(S[2], k.z, sr);
    sr = fmaf(S[3], k.w, sr);
    sr = reduce16(sr);
    float gr = G[0] * m.x;
    gr = fmaf(G[1], m.y, gr);
    gr = fmaf(G[2], m.z, gr);
    gr = fmaf(G[3], m.w, gr);
    gr = reduce16(gr);

    float sdelta = v - sr;
    // S_new = sigmoid(G_old + bs) * S_old + sdelta * k_hat
    S[0] = fmaf(sigm_b(G[0], nbs), S[0], sdelta * k.x);
    S[1] = fmaf(sigm_b(G[1], nbs), S[1], sdelta * k.y);
    S[2] = fmaf(sigm_b(G[2], nbs), S[2], sdelta * k.z);
    S[3] = fmaf(sigm_b(G[3], nbs), S[3], sdelta * k.w);

    float gd = sdelta - gr;
    // G_new = sigmoid(S_new + bg) * G_old + gd * m_hat
    G[0] = fmaf(sigm_b(S[0], nbg), G[0], gd * m.x);
    G[1] = fmaf(sigm_b(S[1], nbg), G[1], gd * m.y);
    G[2] = fmaf(sigm_b(S[2], nbg), G[2], gd * m.z);
    G[3] = fmaf(sigm_b(S[3], nbg), G[3], gd * m.w);

    float sq = S[0] * q.x;
    sq = fmaf(S[1], q.y, sq);
    sq = fmaf(S[2], q.z, sq);
    sq = fmaf(S[3], q.w, sq);
    sq = reduce16(sq);

    if (l == 0)
      outp[(((size_t)t << 4) + b) * 64 + row] = sq * sq * sigm(sq);

    k = kn; q = qn; m = mn; v = vn;
    p = pn;
  }

#pragma unroll
  for (int e = 0; e < 4; ++e) {
    Sout[sgbase + 16 * e] = S[e];
    Gout[sgbase + 16 * e] = G[e];
  }
}

// ---------------------------------------------------------------------------
extern "C" void kernel_launch(void* const* d_in, const int* in_sizes, int n_in,
                              void* d_out, int out_size, void* d_ws, size_t ws_size,
                              hipStream_t stream) {
  const float* x  = (const float*)d_in[0];
  const float* S0 = (const float*)d_in[1];
  const float* G0 = (const float*)d_in[2];
  const float* W  = (const float*)d_in[3];
  const float* bs = (const float*)d_in[4];
  const float* bg = (const float*)d_in[5];
  float* out = (float*)d_out;
  float* proj = (float*)d_ws;               // [M][256] = 32 MB

  const int B = 16, D = 1024;
  const int T = in_sizes[0] / (B * D);      // 2048
  const int M = T * B;                      // 32768

  proj_gemm_mfma<<<dim3(M / GBM), 512, 0, stream>>>(x, W, proj, M, D);

  normalize_km<<<dim3(M / 4), 256, 0, stream>>>(proj, M);

  e81_scan<<<dim3(256), 64, 0, stream>>>(proj, S0, G0, bs, bg, out, T);
}

// Round 7
// 757.196 us; speedup vs baseline: 2.7738x; 1.1695x over previous
//
#include <hip/hip_runtime.h>
#include <hip/hip_bf16.h>

#define EPS 1e-6f

typedef float f32x4 __attribute__((ext_vector_type(4)));
typedef short bf16x8 __attribute__((ext_vector_type(8)));

// ---------------------------------------------------------------------------
// bf16 hi/lo split helpers. u32 element = (lo16 << 16) | hi16.
// ---------------------------------------------------------------------------
__device__ __forceinline__ unsigned f2bf(float x) {
  __hip_bfloat16 h = __float2bfloat16(x);
  return *reinterpret_cast<unsigned short*>(&h);
}
__device__ __forceinline__ unsigned split_pack(float x) {
  unsigned hi = f2bf(x);
  unsigned short hs = (unsigned short)hi;
  float hif = __bfloat162float(*reinterpret_cast<__hip_bfloat16*>(&hs));
  unsigned lo = f2bf(x - hif);
  return (lo << 16) | hi;
}

union FragCast { unsigned u[4]; bf16x8 v; };

// ---------------------------------------------------------------------------
// Kernel 1: proj = x @ W^T via bf16-split MFMA. (unchanged, measured-good)
// ---------------------------------------------------------------------------
constexpr int GBM = 128, GBK = 32;

__global__ __launch_bounds__(512) void proj_gemm_mfma(
    const float* __restrict__ A,   // [M][1024]  x
    const float* __restrict__ Bw,  // [256][1024] W_kvqm
    float* __restrict__ C,         // [M][256]   proj
    int M, int K) {
  __shared__ unsigned As[GBM * GBK];
  __shared__ unsigned Bs[256 * GBK];

  const int tid  = threadIdx.x;
  const int lane = tid & 63;
  const int wid  = tid >> 6;
  const int m0   = blockIdx.x * GBM;
  const int wm   = (wid >> 2) * 64;
  const int wn   = (wid & 3) * 64;

  const int ar = tid >> 2, ak = (tid & 3) * 8;
  const int br = tid >> 1, bk = (tid & 1) * 16;

  f32x4 acc[4][4] = {};

  for (int k0 = 0; k0 < K; k0 += GBK) {
    {
      const float* src = &A[(size_t)(m0 + ar) * K + k0 + ak];
      float4 v0 = *(const float4*)(src);
      float4 v1 = *(const float4*)(src + 4);
      unsigned p0[4] = {split_pack(v0.x), split_pack(v0.y),
                        split_pack(v0.z), split_pack(v0.w)};
      unsigned p1[4] = {split_pack(v1.x), split_pack(v1.y),
                        split_pack(v1.z), split_pack(v1.w)};
      unsigned swz  = (unsigned)(ar & 7) << 4;
      char* base = (char*)As + ar * 128;
      *(uint4*)(base + (((unsigned)ak * 4) ^ swz))       = *(uint4*)p0;
      *(uint4*)(base + (((unsigned)(ak + 4) * 4) ^ swz)) = *(uint4*)p1;
    }
    {
      const float* src = &Bw[(size_t)br * K + k0 + bk];
      unsigned swz = (unsigned)(br & 7) << 4;
      char* base = (char*)Bs + br * 128;
#pragma unroll
      for (int q = 0; q < 4; ++q) {
        float4 v = *(const float4*)(src + q * 4);
        unsigned p[4] = {split_pack(v.x), split_pack(v.y),
                         split_pack(v.z), split_pack(v.w)};
        *(uint4*)(base + (((unsigned)(bk + q * 4) * 4) ^ swz)) = *(uint4*)p;
      }
    }
    __syncthreads();

    unsigned ah[4][4], al[4][4];
    const unsigned ko = ((unsigned)(lane >> 4)) * 16;
#pragma unroll
    for (int mf = 0; mf < 4; ++mf) {
      int r = wm + mf * 16 + (lane & 15);
      unsigned swz = (unsigned)(r & 7) << 4;
      char* base = (char*)As + r * 128;
      uint4 w0 = *(uint4*)(base + (ko ^ swz));
      uint4 w1 = *(uint4*)(base + ((64 + ko) ^ swz));
      ah[mf][0] = __builtin_amdgcn_perm(w0.y, w0.x, 0x05040100);
      al[mf][0] = __builtin_amdgcn_perm(w0.y, w0.x, 0x07060302);
      ah[mf][1] = __builtin_amdgcn_perm(w0.w, w0.z, 0x05040100);
      al[mf][1] = __builtin_amdgcn_perm(w0.w, w0.z, 0x07060302);
      ah[mf][2] = __builtin_amdgcn_perm(w1.y, w1.x, 0x05040100);
      al[mf][2] = __builtin_amdgcn_perm(w1.y, w1.x, 0x07060302);
      ah[mf][3] = __builtin_amdgcn_perm(w1.w, w1.z, 0x05040100);
      al[mf][3] = __builtin_amdgcn_perm(w1.w, w1.z, 0x07060302);
    }

#pragma unroll
    for (int nf = 0; nf < 4; ++nf) {
      int r = wn + nf * 16 + (lane & 15);
      unsigned swz = (unsigned)(r & 7) << 4;
      char* base = (char*)Bs + r * 128;
      uint4 w0 = *(uint4*)(base + (ko ^ swz));
      uint4 w1 = *(uint4*)(base + ((64 + ko) ^ swz));
      FragCast bh, bl;
      bh.u[0] = __builtin_amdgcn_perm(w0.y, w0.x, 0x05040100);
      bl.u[0] = __builtin_amdgcn_perm(w0.y, w0.x, 0x07060302);
      bh.u[1] = __builtin_amdgcn_perm(w0.w, w0.z, 0x05040100);
      bl.u[1] = __builtin_amdgcn_perm(w0.w, w0.z, 0x07060302);
      bh.u[2] = __builtin_amdgcn_perm(w1.y, w1.x, 0x05040100);
      bl.u[2] = __builtin_amdgcn_perm(w1.y, w1.x, 0x07060302);
      bh.u[3] = __builtin_amdgcn_perm(w1.w, w1.z, 0x05040100);
      bl.u[3] = __builtin_amdgcn_perm(w1.w, w1.z, 0x07060302);
#pragma unroll
      for (int mf = 0; mf < 4; ++mf) {
        FragCast fah, fal;
        fah.u[0] = ah[mf][0]; fah.u[1] = ah[mf][1];
        fah.u[2] = ah[mf][2]; fah.u[3] = ah[mf][3];
        fal.u[0] = al[mf][0]; fal.u[1] = al[mf][1];
        fal.u[2] = al[mf][2]; fal.u[3] = al[mf][3];
        acc[mf][nf] = __builtin_amdgcn_mfma_f32_16x16x32_bf16(
            fah.v, bh.v, acc[mf][nf], 0, 0, 0);
        acc[mf][nf] = __builtin_amdgcn_mfma_f32_16x16x32_bf16(
            fah.v, bl.v, acc[mf][nf], 0, 0, 0);
        acc[mf][nf] = __builtin_amdgcn_mfma_f32_16x16x32_bf16(
            fal.v, bh.v, acc[mf][nf], 0, 0, 0);
      }
    }
    __syncthreads();
  }

#pragma unroll
  for (int mf = 0; mf < 4; ++mf) {
    int row = m0 + wm + mf * 16 + (lane >> 4) * 4;
#pragma unroll
    for (int nf = 0; nf < 4; ++nf) {
      int col = wn + nf * 16 + (lane & 15);
#pragma unroll
      for (int r = 0; r < 4; ++r)
        C[(size_t)(row + r) * 256 + col] = acc[mf][nf][r];
    }
  }
}

// ---------------------------------------------------------------------------
// DPP helpers
// ---------------------------------------------------------------------------
template <int CTRL>
__device__ __forceinline__ float dpp_mov(float v) {
  return __int_as_float(
      __builtin_amdgcn_update_dpp(0, __float_as_int(v), CTRL, 0xF, 0xF, true));
}

__device__ __forceinline__ float wave_sum_all(float v) {
  v += dpp_mov<0x121>(v);
  v += dpp_mov<0x122>(v);
  v += dpp_mov<0x124>(v);
  v += dpp_mov<0x128>(v);
  v += dpp_mov<0x142>(v);
  v += dpp_mov<0x143>(v);
  return __int_as_float(__builtin_amdgcn_readlane(__float_as_int(v), 63));
}

// 16-lane-row sum: 4 row_ror hops, result in all lanes of each 16-row.
__device__ __forceinline__ float reduce16(float v) {
  v += dpp_mov<0x121>(v);
  v += dpp_mov<0x122>(v);
  v += dpp_mov<0x124>(v);
  v += dpp_mov<0x128>(v);
  return v;
}

#define L2E 1.4426950408889634f
__device__ __forceinline__ float sigm_b(float x, float nb) {
  float t = __builtin_amdgcn_exp2f(fmaf(x, -L2E, nb));
  return __builtin_amdgcn_rcpf(1.0f + t);
}
__device__ __forceinline__ float sigm(float x) {
  float t = __builtin_amdgcn_exp2f(x * -L2E);
  return __builtin_amdgcn_rcpf(1.0f + t);
}

// ---------------------------------------------------------------------------
// Kernel 2: normalize k,m and permute k,q,m in-place to e-major order.
// ---------------------------------------------------------------------------
__global__ __launch_bounds__(256) void normalize_km(float* __restrict__ proj,
                                                    int rows) {
  const int w = blockIdx.x * 4 + (threadIdx.x >> 6);
  const int lane = threadIdx.x & 63;
  if (w >= rows) return;
  float* p = proj + (size_t)w * 256;
  const int src = 16 * (lane & 3) + (lane >> 2);
  float k = p[src];
  float q = p[128 + src];
  float m = p[192 + src];
  float nk = sqrtf(wave_sum_all(k * k)) + EPS;
  float nm = sqrtf(wave_sum_all(m * m)) + EPS;
  p[lane]       = k * __builtin_amdgcn_rcpf(nk);
  p[128 + lane] = q;
  p[192 + lane] = m * __builtin_amdgcn_rcpf(nm);
}

// ---------------------------------------------------------------------------
// Kernel 3: scan, 4 rows/wave, depth-2 prefetch (2x-unrolled loop),
// explicit schedule: gateS before sr-reduce, sq-reduce before G update.
// Stores RAW sq; out_act applies x^2*sigmoid(x) afterwards.
// ---------------------------------------------------------------------------
#define PSTR 4096  // floats per timestep in proj (16 b * 256)

__global__ __launch_bounds__(64) void e81_scan(
    const float* __restrict__ proj,
    const float* __restrict__ S0,
    const float* __restrict__ G0,
    const float* __restrict__ bsg,
    const float* __restrict__ bgg,
    float* __restrict__ dout,
    int T) {
  const int lane = threadIdx.x;
  const int l = lane & 15;
  const int g = lane >> 4;
  const int b  = blockIdx.x >> 4;
  const int wb = blockIdx.x & 15;
  const int row = wb * 4 + g;

  const size_t sgbase = ((size_t)(b * 64 + row)) * 64 + l;
  float S[4], G[4];
#pragma unroll
  for (int e = 0; e < 4; ++e) {
    S[e] = S0[sgbase + 16 * e];
    G[e] = G0[sgbase + 16 * e];
  }
  const float nbs = -bsg[row] * L2E;
  const float nbg = -bgg[row] * L2E;

  float* outp = dout;
  float* Sout = dout + (size_t)T * 16 * 64;
  float* Gout = Sout + 16 * 64 * 64;

  const float* pA = proj + b * 256;        // even t
  const float* pB = pA + PSTR;             // odd t
  float4 kA = *(const float4*)(pA + 4 * l);
  float4 qA = *(const float4*)(pA + 128 + 4 * l);
  float4 mA = *(const float4*)(pA + 192 + 4 * l);
  float  vA = pA[64 + row];
  float4 kB = *(const float4*)(pB + 4 * l);
  float4 qB = *(const float4*)(pB + 128 + 4 * l);
  float4 mB = *(const float4*)(pB + 192 + 4 * l);
  float  vB = pB[64 + row];

#define STEP(k_, q_, m_, v_, tidx)                                       \
  {                                                                      \
    /* gates from G_old: off the reduce critical path */                 \
    float gs0 = sigm_b(G[0], nbs), gs1 = sigm_b(G[1], nbs);              \
    float gs2 = sigm_b(G[2], nbs), gs3 = sigm_b(G[3], nbs);              \
    float sr = S[0] * k_.x;                                              \
    sr = fmaf(S[1], k_.y, sr);                                           \
    sr = fmaf(S[2], k_.z, sr);                                           \
    sr = fmaf(S[3], k_.w, sr);                                           \
    sr = reduce16(sr);                                                   \
    float gr = G[0] * m_.x;                                              \
    gr = fmaf(G[1], m_.y, gr);                                           \
    gr = fmaf(G[2], m_.z, gr);                                           \
    gr = fmaf(G[3], m_.w, gr);                                           \
    gr = reduce16(gr);                                                   \
    float sdelta = v_ - sr;                                              \
    S[0] = fmaf(gs0, S[0], sdelta * k_.x);                               \
    S[1] = fmaf(gs1, S[1], sdelta * k_.y);                               \
    S[2] = fmaf(gs2, S[2], sdelta * k_.z);                               \
    S[3] = fmaf(gs3, S[3], sdelta * k_.w);                               \
    /* sq reduce first (depends only on S_new); G update fills stalls */ \
    float sq = S[0] * q_.x;                                              \
    sq = fmaf(S[1], q_.y, sq);                                           \
    sq = fmaf(S[2], q_.z, sq);                                           \
    sq = fmaf(S[3], q_.w, sq);                                           \
    sq = reduce16(sq);                                                   \
    float gd = sdelta - gr;                                              \
    G[0] = fmaf(sigm_b(S[0], nbg), G[0], gd * m_.x);                     \
    G[1] = fmaf(sigm_b(S[1], nbg), G[1], gd * m_.y);                     \
    G[2] = fmaf(sigm_b(S[2], nbg), G[2], gd * m_.z);                     \
    G[3] = fmaf(sigm_b(S[3], nbg), G[3], gd * m_.w);                     \
    if (l == 0) outp[(((size_t)(tidx) << 4) + b) * 64 + row] = sq;       \
  }

  for (int t = 0; t < T; t += 2) {
    // depth-2 prefetch: issue t+2 / t+3 now, consume next loop iteration
    const float* pA2 = (t + 2 < T) ? (pA + 2 * PSTR) : pA;
    const float* pB2 = (t + 3 < T) ? (pB + 2 * PSTR) : pB;
    float4 kA2 = *(const float4*)(pA2 + 4 * l);
    float4 qA2 = *(const float4*)(pA2 + 128 + 4 * l);
    float4 mA2 = *(const float4*)(pA2 + 192 + 4 * l);
    float  vA2 = pA2[64 + row];
    float4 kB2 = *(const float4*)(pB2 + 4 * l);
    float4 qB2 = *(const float4*)(pB2 + 128 + 4 * l);
    float4 mB2 = *(const float4*)(pB2 + 192 + 4 * l);
    float  vB2 = pB2[64 + row];

    STEP(kA, qA, mA, vA, t)
    STEP(kB, qB, mB, vB, t + 1)

    kA = kA2; qA = qA2; mA = mA2; vA = vA2; pA = pA2;
    kB = kB2; qB = qB2; mB = mB2; vB = vB2; pB = pB2;
  }
#undef STEP

#pragma unroll
  for (int e = 0; e < 4; ++e) {
    Sout[sgbase + 16 * e] = S[e];
    Gout[sgbase + 16 * e] = G[e];
  }
}

// ---------------------------------------------------------------------------
// Kernel 4: out = x^2 * sigmoid(x) elementwise over the raw sq values.
// ---------------------------------------------------------------------------
__global__ __launch_bounds__(256) void out_act(float* __restrict__ o, int n4) {
  int i = blockIdx.x * 256 + threadIdx.x;
  if (i < n4) {
    float4 x = *(float4*)(o + 4 * i);
    float4 r;
    r.x = x.x * x.x * sigm(x.x);
    r.y = x.y * x.y * sigm(x.y);
    r.z = x.z * x.z * sigm(x.z);
    r.w = x.w * x.w * sigm(x.w);
    *(float4*)(o + 4 * i) = r;
  }
}

// ---------------------------------------------------------------------------
extern "C" void kernel_launch(void* const* d_in, const int* in_sizes, int n_in,
                              void* d_out, int out_size, void* d_ws, size_t ws_size,
                              hipStream_t stream) {
  const float* x  = (const float*)d_in[0];
  const float* S0 = (const float*)d_in[1];
  const float* G0 = (const float*)d_in[2];
  const float* W  = (const float*)d_in[3];
  const float* bs = (const float*)d_in[4];
  const float* bg = (const float*)d_in[5];
  float* out = (float*)d_out;
  float* proj = (float*)d_ws;

  const int B = 16, D = 1024;
  const int T = in_sizes[0] / (B * D);      // 2048
  const int M = T * B;                      // 32768

  proj_gemm_mfma<<<dim3(M / GBM), 512, 0, stream>>>(x, W, proj, M, D);

  normalize_km<<<dim3(M / 4), 256, 0, stream>>>(proj, M);

  e81_scan<<<dim3(256), 64, 0, stream>>>(proj, S0, G0, bs, bg, out, T);

  const int n4 = T * B * 64 / 4;            // 524288 float4s
  out_act<<<dim3((n4 + 255) / 256), 256, 0, stream>>>(out, n4);
}